// Round 17
// baseline (64.006 us; speedup 1.0000x reference)
//
#include <hip/hip_runtime.h>

typedef __attribute__((ext_vector_type(2))) float f32x2;

#define NS 1024      // N samples
#define MM 64        // M patches
#define CC 4         // C compartments
#define NSTEPS 100
#define CLIPMAX 1e10f

// Broadcast lane k's value to all lanes via v_readlane (setup only).
__device__ __forceinline__ float rdlane(float v, int k) {
    return __uint_as_float(__builtin_amdgcn_readlane(__float_as_uint(v), k));
}
// Force a (wave-uniform) value into an SGPR.
__device__ __forceinline__ float sfirst(float v) {
    return __uint_as_float(__builtin_amdgcn_readfirstlane(__float_as_uint(v)));
}

// One wave per sample, barrier-free. r15's phase-A series collapse + r16's
// LDS p-broadcast + r17: ONE-STAGE SOFTWARE PIPELINE.
// Key dataflow fact: rho'[1..3] (and the l=0 pre-sum c0) depend only on rho,
// NOT on ninf -> next step's r1 is available at the TOP of each iteration.
// So per iteration t:
//   store traj | phase-C pre-sums | rh'[1..3] | p_{t+1}=f(r1') | ds_write
//   buf[(t+1)&1] | phase B from pv (PRE-LOADED last iter) | ninf | rh'[0] |
//   ds_read buf[(t+1)&1] -> pv for the NEXT iteration.
// Double-buffered pbuf kills the false WAR dep; the ~120-cyc LDS round trip
// gets a full iteration (~250 cyc) to complete -> off the critical path.
extern "C" __global__
__attribute__((amdgpu_flat_work_group_size(64, 64), amdgpu_waves_per_eu(1, 1)))
void metapop_kernel(
    const float* __restrict__ R,     // (NS, MM, MM)
    const float* __restrict__ T,     // (NS, CC, CC)
    const float* __restrict__ rho0,  // (NS, MM, CC)
    const float* __restrict__ beta,  // (NS,)
    float* __restrict__ out)         // (NSTEPS, NS, MM, CC)
{
    const int n    = blockIdx.x;
    const int lane = threadIdx.x;    // 0..63

    __shared__ float pbuf[2][MM];

    const float* Rn = R + (size_t)n * (MM * MM);

    // ---- Rrow pairs: Rrow2[k2] = (R[n,lane,2k2], R[n,lane,2k2+1]) ----
    f32x2 Rrow2[32];
    {
        const float4* p4 = (const float4*)(Rn + lane * MM);
        #pragma unroll
        for (int q = 0; q < 16; ++q) {
            float4 v = p4[q];
            Rrow2[2*q]   = (f32x2){v.x, v.y};
            Rrow2[2*q+1] = (f32x2){v.z, v.w};
        }
    }

    // ---- ntot[lane] = sum_i R[n,i,lane] ----
    float nt = 0.f;
    #pragma unroll
    for (int i = 0; i < MM; ++i) nt += Rn[i * MM + lane];
    const float binv = beta[n] / nt;   // lane j holds beta/ntot[j]

    // ---- G power sums via the transpose bijection (G dies here) ----
    // Rt[n,i,j] = R[(i&15)*64+j, (n&15)*4+(i>>4), n>>4]
    float S1 = 0.f, S2 = 0.f, S3 = 0.f, S4 = 0.f;
    {
        const int q     = n >> 4;
        const int a     = ((n & 15) << 2) + (lane >> 4);
        const int sbase = (lane & 15) << 6;
        #pragma unroll
        for (int j = 0; j < MM; ++j) {
            float g  = R[(size_t)(sbase + j) * (MM * MM) + a * MM + q]
                     * rdlane(binv, j);
            float g2 = g * g;
            S1 += g;  S2 += g2;  S3 += g2 * g;  S4 += g2 * g2;
        }
    }
    const float T1 = S1, T2 = 0.5f * S2,
                T3 = (1.f / 3.f) * S3, T4 = 0.25f * S4;

    // ---- keep Rrow resident ----
    #pragma unroll
    for (int q = 0; q < 32; ++q) asm volatile("" : "+v"(Rrow2[q]));

    // ---- T[n]: wave-uniform -> SGPRs ----
    float tt[CC][CC];
    {
        const float* Tn = T + n * (CC * CC);
        #pragma unroll
        for (int k = 0; k < CC; ++k)
            #pragma unroll
            for (int l = 0; l < CC; ++l)
                tt[k][l] = sfirst(Tn[k * CC + l]);
    }

    // ---- rho0 ----
    float rh0, rh1, rh2, rh3;
    {
        float4 v = *(const float4*)(rho0 + (size_t)n * (MM * CC) + lane * CC);
        rh0 = v.x; rh1 = v.y; rh2 = v.z; rh3 = v.w;
    }

    float* ob = out + (size_t)n * (MM * CC) + lane * CC;
    const size_t stride = (size_t)NS * MM * CC;

    // ---- pipeline preheader: p_0 -> buf[0] -> pv ----
    float4 pv[16];
    {
        const float h0 = T1 + rh1 * (T2 + rh1 * (T3 + rh1 * T4));
        pbuf[0][lane] = 1.f - __expf(-(rh1 * h0));
        const float4* pb4 = (const float4*)pbuf[0];
        #pragma unroll
        for (int q = 0; q < 16; ++q) pv[q] = pb4[q];
    }

    for (int step = 0; step < NSTEPS; ++step) {
        // (a) trajectory records PRE-update state; fire-and-forget
        *(float4*)(ob + (size_t)step * stride) =
            make_float4(rh0, rh1, rh2, rh3);

        // (b) phase-C pre-sums (depend only on current rho)
        const float c0 = rh0*tt[0][0] + rh1*tt[1][0] + rh2*tt[2][0] + rh3*tt[3][0];
        const float c1 = rh0*tt[0][1] + rh1*tt[1][1] + rh2*tt[2][1] + rh3*tt[3][1];
        const float c2 = rh0*tt[0][2] + rh1*tt[1][2] + rh2*tt[2][2] + rh3*tt[3][2];
        const float c3 = rh0*tt[0][3] + rh1*tt[1][3] + rh2*tt[2][3] + rh3*tt[3][3];

        // (c) next-step rho[1..3] available NOW
        const float nrh1 = fminf(fmaxf(c1, 0.f), CLIPMAX);
        const float nrh2 = fminf(fmaxf(c2, 0.f), CLIPMAX);
        const float nrh3 = fminf(fmaxf(c3, 0.f), CLIPMAX);

        // (d) NEXT step's p, written to the other buffer
        {
            const float hn = T1 + nrh1 * (T2 + nrh1 * (T3 + nrh1 * T4));
            pbuf[(step + 1) & 1][lane] = 1.f - __expf(-(nrh1 * hn));
        }

        // (e) phase B for THIS step from pre-loaded pv; 4 packed chains
        f32x2 a0 = {0.f, 0.f}, a1 = {0.f, 0.f}, a2 = {0.f, 0.f}, a3 = {0.f, 0.f};
        #pragma unroll
        for (int q = 0; q < 4; ++q) {
            float4 pvv;
            pvv = pv[q];
            a0 += Rrow2[2*q]      * (f32x2){pvv.x, pvv.y};
            a0 += Rrow2[2*q + 1]  * (f32x2){pvv.z, pvv.w};
            pvv = pv[q + 4];
            a1 += Rrow2[2*q + 8]  * (f32x2){pvv.x, pvv.y};
            a1 += Rrow2[2*q + 9]  * (f32x2){pvv.z, pvv.w};
            pvv = pv[q + 8];
            a2 += Rrow2[2*q + 16] * (f32x2){pvv.x, pvv.y};
            a2 += Rrow2[2*q + 17] * (f32x2){pvv.z, pvv.w};
            pvv = pv[q + 12];
            a3 += Rrow2[2*q + 24] * (f32x2){pvv.x, pvv.y};
            a3 += Rrow2[2*q + 25] * (f32x2){pvv.z, pvv.w};
        }
        const f32x2 aa = (a0 + a1) + (a2 + a3);
        const float ssum = aa.x + aa.y;
        const float sr   = (rh0 + rh1) + (rh2 + rh3);
        const float ninf = (1.f - sr) * ssum;
        const float nrh0 = fminf(fmaxf(c0 + ninf, 0.f), CLIPMAX);

        // (f) pre-load pv for the NEXT step (buffer written in (d); the
        //     ~120-cyc LDS latency has all of next iter's (a)-(d) to hide)
        {
            const float4* pb4 = (const float4*)pbuf[(step + 1) & 1];
            #pragma unroll
            for (int q = 0; q < 16; ++q) pv[q] = pb4[q];
            #pragma unroll
            for (int q = 0; q < 16; ++q)
                asm volatile("" : "+v"(pv[q].x), "+v"(pv[q].y),
                                  "+v"(pv[q].z), "+v"(pv[q].w));
        }

        // (g) rotate state
        rh0 = nrh0; rh1 = nrh1; rh2 = nrh2; rh3 = nrh3;
    }
}

extern "C" void kernel_launch(void* const* d_in, const int* in_sizes, int n_in,
                              void* d_out, int out_size, void* d_ws, size_t ws_size,
                              hipStream_t stream) {
    const float* R    = (const float*)d_in[0];
    const float* T    = (const float*)d_in[1];
    const float* rho0 = (const float*)d_in[2];
    const float* beta = (const float*)d_in[3];
    float* out = (float*)d_out;
    hipLaunchKernelGGL(metapop_kernel, dim3(NS), dim3(64), 0, stream,
                       R, T, rho0, beta, out);
}

// Round 18
// 58.257 us; speedup vs baseline: 1.0987x; 1.0987x over previous
//
#include <hip/hip_runtime.h>

typedef __attribute__((ext_vector_type(2))) float f32x2;

#define NS 1024      // N samples
#define MM 64        // M patches
#define CC 4         // C compartments
#define NSTEPS 100
#define CLIPMAX 1e10f

// Broadcast lane k's value to all lanes via v_readlane (setup only).
__device__ __forceinline__ float rdlane(float v, int k) {
    return __uint_as_float(__builtin_amdgcn_readlane(__float_as_uint(v), k));
}
// Force a (wave-uniform) value into an SGPR.
__device__ __forceinline__ float sfirst(float v) {
    return __uint_as_float(__builtin_amdgcn_readfirstlane(__float_as_uint(v)));
}

// One wave per sample, barrier-free. r15 series phase-A + r16 LDS broadcast +
// r18: one-stage software pipeline, CORRECTLY scheduled (r17's failure was
// asm pins on pv forcing lgkmcnt(0) at the loop bottom + 184 VGPRs).
//  * 16 ds_reads issue at the TOP of each iteration, reading the buffer
//    written at the END of the previous one -> a full iteration of VALU work
//    (store, c-sums, poly, exp, ds_write) hides the ~120-cyc LDS latency;
//    first-use s_waitcnt never blocks.
//  * Unrolled x2 with DISTINCT buffers bufA/bufB (no parity arithmetic) so
//    write/read non-aliasing is syntactically obvious to LLVM.
//  * No pins on pv; only the proven Rrow residency pins.
extern "C" __global__
__attribute__((amdgpu_flat_work_group_size(64, 64), amdgpu_waves_per_eu(1, 1)))
void metapop_kernel(
    const float* __restrict__ R,     // (NS, MM, MM)
    const float* __restrict__ T,     // (NS, CC, CC)
    const float* __restrict__ rho0,  // (NS, MM, CC)
    const float* __restrict__ beta,  // (NS,)
    float* __restrict__ out)         // (NSTEPS, NS, MM, CC)
{
    const int n    = blockIdx.x;
    const int lane = threadIdx.x;    // 0..63

    __shared__ float bufA[MM];
    __shared__ float bufB[MM];

    const float* Rn = R + (size_t)n * (MM * MM);

    // ---- Rrow pairs ----
    f32x2 Rrow2[32];
    {
        const float4* p4 = (const float4*)(Rn + lane * MM);
        #pragma unroll
        for (int q = 0; q < 16; ++q) {
            float4 v = p4[q];
            Rrow2[2*q]   = (f32x2){v.x, v.y};
            Rrow2[2*q+1] = (f32x2){v.z, v.w};
        }
    }

    // ---- ntot[lane] = sum_i R[n,i,lane] ----
    float nt = 0.f;
    #pragma unroll
    for (int i = 0; i < MM; ++i) nt += Rn[i * MM + lane];
    const float binv = beta[n] / nt;

    // ---- G power sums (G dies here; series coefficients survive) ----
    // Rt[n,i,j] = R[(i&15)*64+j, (n&15)*4+(i>>4), n>>4]
    float S1 = 0.f, S2 = 0.f, S3 = 0.f, S4 = 0.f;
    {
        const int q     = n >> 4;
        const int a     = ((n & 15) << 2) + (lane >> 4);
        const int sbase = (lane & 15) << 6;
        #pragma unroll
        for (int j = 0; j < MM; ++j) {
            float g  = R[(size_t)(sbase + j) * (MM * MM) + a * MM + q]
                     * rdlane(binv, j);
            float g2 = g * g;
            S1 += g;  S2 += g2;  S3 += g2 * g;  S4 += g2 * g2;
        }
    }
    const float T1 = S1, T2 = 0.5f * S2,
                T3 = (1.f / 3.f) * S3, T4 = 0.25f * S4;

    #pragma unroll
    for (int q = 0; q < 32; ++q) asm volatile("" : "+v"(Rrow2[q]));

    // ---- T[n] -> SGPRs ----
    float tt[CC][CC];
    {
        const float* Tn = T + n * (CC * CC);
        #pragma unroll
        for (int k = 0; k < CC; ++k)
            #pragma unroll
            for (int l = 0; l < CC; ++l)
                tt[k][l] = sfirst(Tn[k * CC + l]);
    }

    // ---- rho0 ----
    float rh0, rh1, rh2, rh3;
    {
        float4 v = *(const float4*)(rho0 + (size_t)n * (MM * CC) + lane * CC);
        rh0 = v.x; rh1 = v.y; rh2 = v.z; rh3 = v.w;
    }

    float* ob = out + (size_t)n * (MM * CC) + lane * CC;
    const size_t stride = (size_t)NS * MM * CC;

    // ---- preheader: p_0 -> bufA ----
    {
        const float h0 = T1 + rh1 * (T2 + rh1 * (T3 + rh1 * T4));
        bufA[lane] = 1.f - __expf(-(rh1 * h0));
    }

    // One pipelined step: reads p_t from RD (written last iter), writes
    // p_{t+1} to WR. Returns updated state by reference.
    auto body = [&](const float* __restrict__ RD, float* __restrict__ WR,
                    int step) {
        // (1) issue p reads for THIS step (data written ~1 iteration ago)
        float4 pv[16];
        {
            const float4* pb4 = (const float4*)RD;
            #pragma unroll
            for (int q = 0; q < 16; ++q) pv[q] = pb4[q];
        }

        // (2) trajectory store (pre-update state)
        *(float4*)(ob + (size_t)step * stride) =
            make_float4(rh0, rh1, rh2, rh3);

        // (3) phase-C pre-sums + next rho[1..3]
        const float c0 = rh0*tt[0][0] + rh1*tt[1][0] + rh2*tt[2][0] + rh3*tt[3][0];
        const float c1 = rh0*tt[0][1] + rh1*tt[1][1] + rh2*tt[2][1] + rh3*tt[3][1];
        const float c2 = rh0*tt[0][2] + rh1*tt[1][2] + rh2*tt[2][2] + rh3*tt[3][2];
        const float c3 = rh0*tt[0][3] + rh1*tt[1][3] + rh2*tt[2][3] + rh3*tt[3][3];
        const float nrh1 = fminf(fmaxf(c1, 0.f), CLIPMAX);
        const float nrh2 = fminf(fmaxf(c2, 0.f), CLIPMAX);
        const float nrh3 = fminf(fmaxf(c3, 0.f), CLIPMAX);

        // (4) NEXT step's p -> the other buffer
        {
            const float hn = T1 + nrh1 * (T2 + nrh1 * (T3 + nrh1 * T4));
            WR[lane] = 1.f - __expf(-(nrh1 * hn));
        }

        // (5) phase B matvec on pv (first use of the reads issued in (1))
        f32x2 a0 = {0.f, 0.f}, a1 = {0.f, 0.f}, a2 = {0.f, 0.f}, a3 = {0.f, 0.f};
        #pragma unroll
        for (int q = 0; q < 4; ++q) {
            float4 pvv;
            pvv = pv[q];
            a0 += Rrow2[2*q]      * (f32x2){pvv.x, pvv.y};
            a0 += Rrow2[2*q + 1]  * (f32x2){pvv.z, pvv.w};
            pvv = pv[q + 4];
            a1 += Rrow2[2*q + 8]  * (f32x2){pvv.x, pvv.y};
            a1 += Rrow2[2*q + 9]  * (f32x2){pvv.z, pvv.w};
            pvv = pv[q + 8];
            a2 += Rrow2[2*q + 16] * (f32x2){pvv.x, pvv.y};
            a2 += Rrow2[2*q + 17] * (f32x2){pvv.z, pvv.w};
            pvv = pv[q + 12];
            a3 += Rrow2[2*q + 24] * (f32x2){pvv.x, pvv.y};
            a3 += Rrow2[2*q + 25] * (f32x2){pvv.z, pvv.w};
        }
        const f32x2 aa = (a0 + a1) + (a2 + a3);
        const float ssum = aa.x + aa.y;
        const float sr   = (rh0 + rh1) + (rh2 + rh3);
        const float ninf = (1.f - sr) * ssum;

        // (6) rotate state
        rh0 = fminf(fmaxf(c0 + ninf, 0.f), CLIPMAX);
        rh1 = nrh1; rh2 = nrh2; rh3 = nrh3;
    };

    #pragma unroll 1
    for (int it = 0; it < NSTEPS / 2; ++it) {
        body(bufA, bufB, 2 * it);       // even step: read A, write B
        body(bufB, bufA, 2 * it + 1);   // odd  step: read B, write A
    }
}

extern "C" void kernel_launch(void* const* d_in, const int* in_sizes, int n_in,
                              void* d_out, int out_size, void* d_ws, size_t ws_size,
                              hipStream_t stream) {
    const float* R    = (const float*)d_in[0];
    const float* T    = (const float*)d_in[1];
    const float* rho0 = (const float*)d_in[2];
    const float* beta = (const float*)d_in[3];
    float* out = (float*)d_out;
    hipLaunchKernelGGL(metapop_kernel, dim3(NS), dim3(64), 0, stream,
                       R, T, rho0, beta, out);
}